// Round 6
// baseline (117.314 us; speedup 1.0000x reference)
//
#include <hip/hip_runtime.h>

// out[b,n] = relu( sum_d x[b, idx[n,d]] * w[n,d] )
//   x: (B=256, N=16384) f32, w: (N,32) f32, idx: (N,32) i32, out: (B,N) f32
//
// R15: eliminate the prep kernel. Evidence so far: gather is pinned at
// ~30us by {LDS b64 random-gather service ~13us + dependent-chain latency
// at the 16-wave/CU cap imposed by the 128KiB image}; R14 proved smaller-
// image/higher-occupancy raises the LDS instruction floor more than it
// saves; R10/R11/R13 proved source scheduling is compiler-owned. The last
// real lever is the prep dispatch (~4us) + gap (~1.5us) + pw4 L2 round
// trip: the hot loop now reads idx/w rows DIRECTLY (8x int4 + 8x float4
// per column; lanes stride 128B, 16 back-to-back wave-loads consume every
// 64B sector exactly once; each row is touched by exactly one split
// block). cvt_pkrtz(w,w) reproduces prep's RTZ f16 conversion bit-exactly;
// gather order, lo/hi sequence, and the a(d<16)/c(d>=16) split are
// unchanged -> absmax identical to R9-R14. Workspace now unused.

#define NB   16384
#define DEG  32

typedef __fp16 hp2 __attribute__((ext_vector_type(2)));  // cvt_pkrtz result type

__device__ __forceinline__ unsigned pk16(float a, float b) {
    return __builtin_bit_cast(unsigned, (hp2)__builtin_amdgcn_cvt_pkrtz(a, b));
}

// Load idx/w rows for column nn: 8x int4 + 8x float4 (per-lane contiguous
// 128B row, lane-strided; sectors fully consumed across the 16 loads).
#define LOADIW(nn)                                                         \
    do {                                                                   \
        const int4*   ip_ = (const int4*)(idx + (size_t)(nn) * DEG);       \
        const float4* wp_ = (const float4*)(w   + (size_t)(nn) * DEG);     \
        _Pragma("unroll") for (int k_ = 0; k_ < 8; ++k_) {                 \
            I[k_] = ip_[k_];                                               \
            W[k_] = wp_[k_];                                               \
        }                                                                  \
    } while (0)

// One d-pair: 2 ds_read_b64 gathers + 2 cvt_pkrtz + 4 v_pk_fma_f16.
// Identical FP op sequence to R11's ACC2 halves (lo then hi).
#define PAIR(jA, jB, wA, wB, r01, r23)                                     \
    {                                                                      \
        const uint2 g0_ = lds[(unsigned)(jA)];                             \
        const uint2 g1_ = lds[(unsigned)(jB)];                             \
        const hp2 wlo_ = (hp2)__builtin_amdgcn_cvt_pkrtz(wA, wA);          \
        const hp2 whi_ = (hp2)__builtin_amdgcn_cvt_pkrtz(wB, wB);          \
        r01 += wlo_ * __builtin_bit_cast(hp2, g0_.x);                      \
        r23 += wlo_ * __builtin_bit_cast(hp2, g0_.y);                      \
        r01 += whi_ * __builtin_bit_cast(hp2, g1_.x);                      \
        r23 += whi_ * __builtin_bit_cast(hp2, g1_.y);                      \
    }

// One int4/float4 = 4 d-entries = 2 pairs.
#define QUAD(K, r01, r23)                                                  \
    PAIR(I[K].x, I[K].y, W[K].x, W[K].y, r01, r23)                         \
    PAIR(I[K].z, I[K].w, W[K].z, W[K].w, r01, r23)

// One column: row loads, 32 gathers + fma, 4 NT stores.
#define STEP(II, LD)                                                       \
    {                                                                      \
        const int n = n0 + t + 1024 * (II);                                \
        if (LD) LOADIW(n);                                                 \
        hp2 a01 = {0, 0}, a23 = {0, 0}, c01 = {0, 0}, c23 = {0, 0};        \
        QUAD(0, a01, a23)                                                  \
        QUAD(1, a01, a23)                                                  \
        QUAD(2, a01, a23)                                                  \
        QUAD(3, a01, a23)                                                  \
        QUAD(4, c01, c23)                                                  \
        QUAD(5, c01, c23)                                                  \
        QUAD(6, c01, c23)                                                  \
        QUAD(7, c01, c23)                                                  \
        const hp2 s01 = a01 + c01;                                         \
        const hp2 s23 = a23 + c23;                                         \
        __builtin_nontemporal_store(fmaxf((float)s01.x, 0.f),              \
                                    &out[(size_t)(b0 + 0) * NB + n]);      \
        __builtin_nontemporal_store(fmaxf((float)s01.y, 0.f),              \
                                    &out[(size_t)(b0 + 1) * NB + n]);      \
        __builtin_nontemporal_store(fmaxf((float)s23.x, 0.f),              \
                                    &out[(size_t)(b0 + 2) * NB + n]);      \
        __builtin_nontemporal_store(fmaxf((float)s23.y, 0.f),              \
                                    &out[(size_t)(b0 + 3) * NB + n]);      \
    }

__global__ __launch_bounds__(1024, 4) void gather4_kernel(
    const float* __restrict__ x, const int* __restrict__ idx,
    const float* __restrict__ w, float* __restrict__ out) {
    extern __shared__ uint2 lds[];               // 16384 uint2 = 128 KiB
    const int t  = threadIdx.x;
    const int q  = (int)blockIdx.x & 63;         // quad 0..63 -> b = 4q..4q+3
    const int n0 = ((int)blockIdx.x >> 6) * 4096;  // split-major: XCD = q%8

    // Stage quad j-image straight from x (coalesced float4 per row; rows are
    // L2-hot for 3 of the 4 split-blocks). ds_write_b128 stride-32B: clean.
    const float* xr0 = x + (size_t)(4 * q) * NB;
    const float* xr1 = xr0 + NB;
    const float* xr2 = xr1 + NB;
    const float* xr3 = xr2 + NB;
#pragma unroll
    for (int p = 0; p < 4; ++p) {
        const int j = 4 * (t + 1024 * p);
        const float4 r0 = *(const float4*)&xr0[j];
        const float4 r1 = *(const float4*)&xr1[j];
        const float4 r2 = *(const float4*)&xr2[j];
        const float4 r3 = *(const float4*)&xr3[j];
        uint4 w0, w1;
        w0.x = pk16(r0.x, r1.x); w0.y = pk16(r2.x, r3.x);
        w0.z = pk16(r0.y, r1.y); w0.w = pk16(r2.y, r3.y);
        w1.x = pk16(r0.z, r1.z); w1.y = pk16(r2.z, r3.z);
        w1.z = pk16(r0.w, r1.w); w1.w = pk16(r2.w, r3.w);
        *(uint4*)&lds[j]     = w0;
        *(uint4*)&lds[j + 2] = w1;
    }

    int4   I[8];
    float4 W[8];
    // i=0 row loads issued before the barrier: latency hides under the
    // staging drain + barrier.
    LOADIW(n0 + t);
    __syncthreads();

    const int b0 = 4 * q;
    STEP(0, 0)
    STEP(1, 1)
    STEP(2, 1)
    STEP(3, 1)
}

extern "C" void kernel_launch(void* const* d_in, const int* in_sizes, int n_in,
                              void* d_out, int out_size, void* d_ws, size_t ws_size,
                              hipStream_t stream) {
    const float* x   = (const float*)d_in[0];    // (B, N)
    const float* w   = (const float*)d_in[1];    // (N, DEG)
    const int*   idx = (const int*)d_in[2];      // (N, DEG)
    float* out = (float*)d_out;                  // (B, N)
    (void)d_ws; (void)ws_size;                   // workspace unused in R15

    // allow 128 KiB dynamic LDS (idempotent; host-side, capture-safe)
    (void)hipFuncSetAttribute((const void*)gather4_kernel,
                              hipFuncAttributeMaxDynamicSharedMemorySize, 131072);

    gather4_kernel<<<256, 1024, 131072, stream>>>(x, idx, w, out);
}

// Round 7
// 83.100 us; speedup vs baseline: 1.4117x; 1.4117x over previous
//
#include <hip/hip_runtime.h>

// out[b,n] = relu( sum_d x[b, idx[n,d]] * w[n,d] )
//   x: (B=256, N=16384) f32, w: (N,32) f32, idx: (N,32) i32, out: (B,N) f32
//
// R16: restore best-known (R11, 83.63us). Session ledger:
//   R10 (VMEM half-pipeline + NT stores): null -- compiler sinks prefetch.
//   R11 (uint4 streams, 8 loads/col):     83.63us, best.
//   R12 (coop fusion + grid.sync):        +43us. Gave counters: hot loop
//        <40% LDS-busy, VALU 7%, HBM 8% -> latency-bound at 16 waves/CU.
//   R13 (LDS software pipeline):          null -- schedule compiler-owned.
//   R14 (64KiB b32 image, 32 waves/CU):   +5.6us -- b32 doubles the LDS
//        instruction floor; costs more than latency hiding returns.
//   R15 (drop prep, direct idx/w rows):   +33.7us -- per-lane 128B rows are
//        wave-uncoalesced (64 lines/load); pw4 streams exist for a reason.
// Remaining budget: 44.5us harness workspace fill (fixed) + ~4us prep +
// ~30us gather (LDS b64 random-gather service + dep-chain latency at the
// LDS-capacity-capped occupancy; both image/occupancy directions measured
// worse) + ~5us gaps. This is the structural floor of this formulation.

#define NB   16384
#define DEG  32

typedef __fp16 hp2 __attribute__((ext_vector_type(2)));  // cvt_pkrtz result type

__device__ __forceinline__ unsigned pk16(float a, float b) {
    return __builtin_bit_cast(unsigned, (hp2)__builtin_amdgcn_cvt_pkrtz(a, b));
}

// prep: pack (idx,w) rows into 8 coalesced uint4 streams:
//   pw4[d4][n] = { idxpair(2*d4), wpair(2*d4), idxpair(2*d4+1), wpair(2*d4+1) }
__global__ __launch_bounds__(256) void prep_pw_kernel(
    const int* __restrict__ idx, const float* __restrict__ w,
    uint4* __restrict__ pw4) {
    __shared__ int   idx_s[64][33];
    __shared__ float w_s[64][33];
    const int t  = threadIdx.x;
    const int nb = (int)blockIdx.x * 64;

    const int4*   src  = (const int4*)(idx + (size_t)nb * DEG);
    const float4* srcw = (const float4*)(w   + (size_t)nb * DEG);
#pragma unroll
    for (int p = 0; p < 2; ++p) {
        const int e4 = t + 256 * p;              // int4 index 0..511, coalesced
        const int n0 = e4 >> 3;
        const int c0 = (e4 & 7) * 4;
        const int4 v = src[e4];
        idx_s[n0][c0 + 0] = v.x; idx_s[n0][c0 + 1] = v.y;
        idx_s[n0][c0 + 2] = v.z; idx_s[n0][c0 + 3] = v.w;
        const float4 f = srcw[e4];
        w_s[n0][c0 + 0] = f.x; w_s[n0][c0 + 1] = f.y;
        w_s[n0][c0 + 2] = f.z; w_s[n0][c0 + 3] = f.w;
    }
    __syncthreads();

    const int np    = t & 63;
    const int dbase = t >> 6;                    // 0..3
#pragma unroll
    for (int k = 0; k < 2; ++k) {
        const int d4 = dbase * 2 + k;            // 0..7
        const int c  = 4 * d4;                   // first of 4 d-columns
        uint4 o;
        o.x = (unsigned)idx_s[np][c + 0] | ((unsigned)idx_s[np][c + 1] << 16);
        o.y = pk16(w_s[np][c + 0], w_s[np][c + 1]);
        o.z = (unsigned)idx_s[np][c + 2] | ((unsigned)idx_s[np][c + 3] << 16);
        o.w = pk16(w_s[np][c + 2], w_s[np][c + 3]);
        pw4[(size_t)d4 * NB + nb + np] = o;
    }
}

// Load all 8 uint4 streams for column nn into a register buffer.
#define LOADQ(buf, nn)                                                     \
    do {                                                                   \
        const uint4* p_ = pw4 + (nn);                                      \
        _Pragma("unroll") for (int d4_ = 0; d4_ < 8; ++d4_)                \
            buf[d4_] = p_[(size_t)d4_ * NB];                               \
    } while (0)

// Consume one uint4 = two d2-groups: 4 ds_read_b64 + 8 v_pk_fma_f16.
// FP order matches R9/R10 exactly (d2 even then odd; lo-j then hi-j).
#define ACC2(buf, D4, r01, r23)                                            \
    {                                                                      \
        const unsigned jpA = buf[D4].x;                                    \
        const uint2 gA0 = lds[jpA & 0xffffu];                              \
        const uint2 gA1 = lds[jpA >> 16];                                  \
        const hp2 wA  = __builtin_bit_cast(hp2, buf[D4].y);                \
        const hp2 wAlo = {wA.x, wA.x};                                     \
        const hp2 wAhi = {wA.y, wA.y};                                     \
        r01 += wAlo * __builtin_bit_cast(hp2, gA0.x);                      \
        r23 += wAlo * __builtin_bit_cast(hp2, gA0.y);                      \
        r01 += wAhi * __builtin_bit_cast(hp2, gA1.x);                      \
        r23 += wAhi * __builtin_bit_cast(hp2, gA1.y);                      \
        const unsigned jpB = buf[D4].z;                                    \
        const uint2 gB0 = lds[jpB & 0xffffu];                              \
        const uint2 gB1 = lds[jpB >> 16];                                  \
        const hp2 wB  = __builtin_bit_cast(hp2, buf[D4].w);                \
        const hp2 wBlo = {wB.x, wB.x};                                     \
        const hp2 wBhi = {wB.y, wB.y};                                     \
        r01 += wBlo * __builtin_bit_cast(hp2, gB0.x);                      \
        r23 += wBlo * __builtin_bit_cast(hp2, gB0.y);                      \
        r01 += wBhi * __builtin_bit_cast(hp2, gB1.x);                      \
        r23 += wBhi * __builtin_bit_cast(hp2, gB1.y);                      \
    }

// One i-iteration: optional prefetch of the NEXT iteration's 8 streams into
// NXT, then compute from CUR.
#define STEP(CUR, NXT, I, PF)                                              \
    {                                                                      \
        const int n = n0 + t + 1024 * (I);                                 \
        if (PF) LOADQ(NXT, n + 1024);                                      \
        hp2 a01 = {0, 0}, a23 = {0, 0}, c01 = {0, 0}, c23 = {0, 0};        \
        ACC2(CUR, 0, a01, a23)                                             \
        ACC2(CUR, 1, a01, a23)                                             \
        ACC2(CUR, 2, a01, a23)                                             \
        ACC2(CUR, 3, a01, a23)                                             \
        ACC2(CUR, 4, c01, c23)                                             \
        ACC2(CUR, 5, c01, c23)                                             \
        ACC2(CUR, 6, c01, c23)                                             \
        ACC2(CUR, 7, c01, c23)                                             \
        const hp2 s01 = a01 + c01;                                         \
        const hp2 s23 = a23 + c23;                                         \
        __builtin_nontemporal_store(fmaxf((float)s01.x, 0.f),              \
                                    &out[(size_t)(b0 + 0) * NB + n]);      \
        __builtin_nontemporal_store(fmaxf((float)s01.y, 0.f),              \
                                    &out[(size_t)(b0 + 1) * NB + n]);      \
        __builtin_nontemporal_store(fmaxf((float)s23.x, 0.f),              \
                                    &out[(size_t)(b0 + 2) * NB + n]);      \
        __builtin_nontemporal_store(fmaxf((float)s23.y, 0.f),              \
                                    &out[(size_t)(b0 + 3) * NB + n]);      \
    }

__global__ __launch_bounds__(1024, 4) void gather4_kernel(
    const float* __restrict__ x, const uint4* __restrict__ pw4,
    float* __restrict__ out) {
    extern __shared__ uint2 lds[];               // 16384 uint2 = 128 KiB
    const int t  = threadIdx.x;
    const int q  = (int)blockIdx.x & 63;         // quad 0..63 -> b = 4q..4q+3
    const int n0 = ((int)blockIdx.x >> 6) * 4096;  // split-major: XCD = q%8

    // Stage quad j-image straight from x (coalesced float4 per row; rows are
    // L2-hot for 3 of the 4 split-blocks). ds_write_b128 stride-32B: clean.
    const float* xr0 = x + (size_t)(4 * q) * NB;
    const float* xr1 = xr0 + NB;
    const float* xr2 = xr1 + NB;
    const float* xr3 = xr2 + NB;
#pragma unroll
    for (int p = 0; p < 4; ++p) {
        const int j = 4 * (t + 1024 * p);
        const float4 r0 = *(const float4*)&xr0[j];
        const float4 r1 = *(const float4*)&xr1[j];
        const float4 r2 = *(const float4*)&xr2[j];
        const float4 r3 = *(const float4*)&xr3[j];
        uint4 w0, w1;
        w0.x = pk16(r0.x, r1.x); w0.y = pk16(r2.x, r3.x);
        w0.z = pk16(r0.y, r1.y); w0.w = pk16(r2.y, r3.y);
        w1.x = pk16(r0.z, r1.z); w1.y = pk16(r2.z, r3.z);
        w1.z = pk16(r0.w, r1.w); w1.w = pk16(r2.w, r3.w);
        *(uint4*)&lds[j]     = w0;
        *(uint4*)&lds[j + 2] = w1;
    }

    uint4 U[8], V[8];
    // Prefetch i=0's streams before the barrier: L2 latency hides under the
    // staging lgkmcnt drain + barrier.
    LOADQ(U, n0 + t);
    __syncthreads();

    const int b0 = 4 * q;
    STEP(U, V, 0, 1)
    STEP(V, U, 1, 1)
    STEP(U, V, 2, 1)
    STEP(V, U, 3, 0)
}

extern "C" void kernel_launch(void* const* d_in, const int* in_sizes, int n_in,
                              void* d_out, int out_size, void* d_ws, size_t ws_size,
                              hipStream_t stream) {
    const float* x   = (const float*)d_in[0];    // (B, N)
    const float* w   = (const float*)d_in[1];    // (N, DEG)
    const int*   idx = (const int*)d_in[2];      // (N, DEG)
    float* out = (float*)d_out;                  // (B, N)
    uint4* pw4 = (uint4*)d_ws;                   // [8][N] uint4 = 2 MiB

    // allow 128 KiB dynamic LDS (idempotent; host-side, capture-safe)
    (void)hipFuncSetAttribute((const void*)gather4_kernel,
                              hipFuncAttributeMaxDynamicSharedMemorySize, 131072);

    prep_pw_kernel<<<NB / 64, 256, 0, stream>>>(idx, w, pw4);

    gather4_kernel<<<256, 1024, 131072, stream>>>(x, pw4, out);
}